// Round 1
// baseline (215.156 us; speedup 1.0000x reference)
//
#include <hip/hip_runtime.h>
#include <hip/hip_bf16.h>

#define B_    8
#define S_    4096
#define DIN   512
#define DOUT  64
#define NROWS (B_ * S_)   // 32768

typedef __attribute__((ext_vector_type(8))) short bf16x8;
typedef __attribute__((ext_vector_type(4))) float f32x4;

__device__ __forceinline__ unsigned short f32_to_bf16(float f) {
    union { float f; unsigned int u; } c; c.f = f;
    unsigned int r = (c.u + 0x7FFFu + ((c.u >> 16) & 1u)) >> 16;
    return (unsigned short)r;
}

// ---------------------------------------------------------------------------
// Kernel 1: transpose W_Q|W_K|W_V (each [512][64] f32) -> Wt bf16 [192][512]
// row p*64+n holds W_p[:, n] so the GEMM B-fragment reads are contiguous in K.
// ---------------------------------------------------------------------------
__global__ void wt_convert(const float* __restrict__ WQ,
                           const float* __restrict__ WK,
                           const float* __restrict__ WV,
                           unsigned short* __restrict__ Wt) {
    int idx = blockIdx.x * 256 + threadIdx.x;     // 24576 quads total
    if (idx >= 3 * 512 * 16) return;
    int p   = idx / 8192;                         // 0..2
    int rem = idx - p * 8192;
    int k   = rem >> 4;                           // 0..511
    int n0  = (rem & 15) * 4;                     // 0..60
    const float* W = (p == 0) ? WQ : ((p == 1) ? WK : WV);
    float4 v = *(const float4*)(W + k * 64 + n0);
    Wt[(size_t)(p * 64 + n0 + 0) * 512 + k] = f32_to_bf16(v.x);
    Wt[(size_t)(p * 64 + n0 + 1) * 512 + k] = f32_to_bf16(v.y);
    Wt[(size_t)(p * 64 + n0 + 2) * 512 + k] = f32_to_bf16(v.z);
    Wt[(size_t)(p * 64 + n0 + 3) * 512 + k] = f32_to_bf16(v.w);
}

// ---------------------------------------------------------------------------
// Kernel 2: fused QKV projection. Grid 512 x 256 threads.
// Each block: 64 rows of x; each wave: 16 rows x all 192 output cols.
// A-frags converted f32->bf16 in registers; B-frags read straight from Wt
// (192 KB, L1/L2-resident). Q is pre-scaled by 1/8 (exact pow2) on store.
// ---------------------------------------------------------------------------
__global__ __launch_bounds__(256) void qkv_proj(const float* __restrict__ x,
                                                const unsigned short* __restrict__ Wt,
                                                unsigned short* __restrict__ QKV) {
    const int tid  = threadIdx.x;
    const int lane = tid & 63;
    const int wq   = tid >> 6;       // wave 0..3
    const int c15  = lane & 15;
    const int g    = lane >> 4;      // 0..3
    const int arow = blockIdx.x * 64 + wq * 16 + c15;
    const float* xrow = x + (size_t)arow * DIN;

    f32x4 acc[12] = {};

    for (int ks = 0; ks < 16; ++ks) {
        const float4* ap = (const float4*)(xrow + ks * 32 + g * 8);
        float4 a0 = ap[0], a1 = ap[1];
        bf16x8 af;
        af[0] = (short)f32_to_bf16(a0.x); af[1] = (short)f32_to_bf16(a0.y);
        af[2] = (short)f32_to_bf16(a0.z); af[3] = (short)f32_to_bf16(a0.w);
        af[4] = (short)f32_to_bf16(a1.x); af[5] = (short)f32_to_bf16(a1.y);
        af[6] = (short)f32_to_bf16(a1.z); af[7] = (short)f32_to_bf16(a1.w);
#pragma unroll
        for (int nf = 0; nf < 12; ++nf) {
            bf16x8 bf = *(const bf16x8*)(Wt + (size_t)(nf * 16 + c15) * 512 + ks * 32 + g * 8);
            acc[nf] = __builtin_amdgcn_mfma_f32_16x16x32_bf16(af, bf, acc[nf], 0, 0, 0);
        }
    }

    // D layout: row = 4*g + reg, col = c15 (per 16-col fragment)
    const int orow0 = blockIdx.x * 64 + wq * 16 + g * 4;
#pragma unroll
    for (int nf = 0; nf < 12; ++nf) {
        const int p    = nf >> 2;
        const int ncol = (nf & 3) * 16 + c15;
        unsigned short* outp = QKV + (size_t)p * NROWS * DOUT;
        const float sc = (p == 0) ? 0.125f : 1.0f;   // fold 1/sqrt(64) into Q
#pragma unroll
        for (int r = 0; r < 4; ++r)
            outp[(size_t)(orow0 + r) * DOUT + ncol] = f32_to_bf16(acc[nf][r] * sc);
    }
}

// ---------------------------------------------------------------------------
// Kernel 3: causal flash attention. Grid 512 (8 batches x 64 q-tiles,
// heavy tiles first), 256 threads = 4 waves, each wave owns 16 q rows.
// KV-tile = 64. K and V^T staged in XOR-swizzled LDS; P round-trips through
// per-wave swizzled LDS to convert D-layout -> A-layout for the PV MFMA.
// ---------------------------------------------------------------------------
__global__ __launch_bounds__(256) void attn_fwd(const unsigned short* __restrict__ QKV,
                                                float* __restrict__ out) {
    __shared__ alignas(16) unsigned short k_lds[64 * 64];   // K[kv][d], swizzled
    __shared__ alignas(16) unsigned short v_lds[64 * 64];   // V^T[d][kv], swizzled
    __shared__ alignas(16) unsigned short p_lds[4 * 16 * 64]; // per-wave P, swizzled

    const int bid = blockIdx.x;
    const int b   = bid & 7;
    const int t   = 63 - (bid >> 3);   // heavy q-tiles launch first
    const int q0  = t * 64;
    const int tid = threadIdx.x;
    const int lane = tid & 63;
    const int wq  = tid >> 6;
    const int c15 = lane & 15;
    const int g   = lane >> 4;

    const unsigned short* Qg = QKV + (size_t)b * S_ * DOUT;
    const unsigned short* Kg = QKV + (size_t)NROWS * DOUT + (size_t)b * S_ * DOUT;
    const unsigned short* Vg = QKV + (size_t)2 * NROWS * DOUT + (size_t)b * S_ * DOUT;

    // Q A-frags (row = c15, k = 32*kk + 8*g + j). Q already scaled by 1/8.
    const size_t qoff = (size_t)(q0 + wq * 16 + c15) * DOUT;
    bf16x8 qf0 = *(const bf16x8*)(Qg + qoff + g * 8);
    bf16x8 qf1 = *(const bf16x8*)(Qg + qoff + 32 + g * 8);

    f32x4 oacc[4] = {};
    float m_r[4], l_r[4];
#pragma unroll
    for (int r = 0; r < 4; ++r) { m_r[r] = -3.0e38f; l_r[r] = 0.f; }

    const int ntiles = t + 1;
    for (int it = 0; it < ntiles; ++it) {
        const int k0 = it * 64;
        __syncthreads();   // previous tile's consumers done before restage

        // --- stage K: 64x64 bf16, 16B chunks, XOR-swizzled by row ---
        for (int c = tid; c < 512; c += 256) {
            int row = c >> 3, slot = c & 7;
            bf16x8 val = *(const bf16x8*)(Kg + (size_t)(k0 + row) * DOUT + slot * 8);
            *(bf16x8*)((char*)k_lds + row * 128 + ((slot * 16) ^ ((row & 7) << 4))) = val;
        }
        // --- stage V transposed: Vt[d][kv], XOR-swizzled by d ---
        {
            int kv = tid >> 2;
            int d0 = (tid & 3) * 16;
            const unsigned short* src = Vg + (size_t)(k0 + kv) * DOUT + d0;
            bf16x8 va = *(const bf16x8*)(src);
            bf16x8 vb = *(const bf16x8*)(src + 8);
#pragma unroll
            for (int i = 0; i < 8; ++i) {
                int d = d0 + i;
                *(unsigned short*)((char*)v_lds + d * 128 + ((kv * 2) ^ ((d & 7) << 4))) =
                    (unsigned short)va[i];
            }
#pragma unroll
            for (int i = 0; i < 8; ++i) {
                int d = d0 + 8 + i;
                *(unsigned short*)((char*)v_lds + d * 128 + ((kv * 2) ^ ((d & 7) << 4))) =
                    (unsigned short)vb[i];
            }
        }
        __syncthreads();

        // --- S = Q K^T (16 x 64 per wave) ---
        f32x4 s[4] = {};
#pragma unroll
        for (int nf = 0; nf < 4; ++nf) {
            const int kvr = nf * 16 + c15;
            bf16x8 kf0 = *(const bf16x8*)((char*)k_lds + kvr * 128 + ((g * 16) ^ ((kvr & 7) << 4)));
            bf16x8 kf1 = *(const bf16x8*)((char*)k_lds + kvr * 128 + (((64 + g * 16)) ^ ((kvr & 7) << 4)));
            s[nf] = __builtin_amdgcn_mfma_f32_16x16x32_bf16(qf0, kf0, s[nf], 0, 0, 0);
            s[nf] = __builtin_amdgcn_mfma_f32_16x16x32_bf16(qf1, kf1, s[nf], 0, 0, 0);
        }

        // --- causal mask (diagonal tile only; k0 == q0 here) ---
        if (it == t) {
#pragma unroll
            for (int nf = 0; nf < 4; ++nf) {
                const int col = nf * 16 + c15;
#pragma unroll
                for (int r = 0; r < 4; ++r) {
                    const int rowl = wq * 16 + g * 4 + r;
                    if (col > rowl) s[nf][r] = -1.0e30f;
                }
            }
        }

        // --- online softmax: row max across 64 cols (4 frags x 16 lanes) ---
        float tmax[4];
#pragma unroll
        for (int r = 0; r < 4; ++r)
            tmax[r] = fmaxf(fmaxf(s[0][r], s[1][r]), fmaxf(s[2][r], s[3][r]));
#pragma unroll
        for (int mk = 1; mk < 16; mk <<= 1)
#pragma unroll
            for (int r = 0; r < 4; ++r)
                tmax[r] = fmaxf(tmax[r], __shfl_xor(tmax[r], mk, 64));

        float alpha[4], tsum[4];
#pragma unroll
        for (int r = 0; r < 4; ++r) {
            float mn = fmaxf(m_r[r], tmax[r]);
            alpha[r] = __expf(m_r[r] - mn);
            m_r[r]   = mn;
            tsum[r]  = 0.f;
        }

        // --- P = exp(S - m), write to per-wave swizzled LDS (D->A transpose) ---
#pragma unroll
        for (int nf = 0; nf < 4; ++nf) {
#pragma unroll
            for (int r = 0; r < 4; ++r) {
                float p = __expf(s[nf][r] - m_r[r]);
                tsum[r] += p;
                const int rowl = g * 4 + r;
                *(unsigned short*)((char*)p_lds + wq * 2048 + rowl * 128 +
                                   ((((nf * 16 + c15) * 2)) ^ ((rowl & 7) << 4))) = f32_to_bf16(p);
            }
        }
#pragma unroll
        for (int mk = 1; mk < 16; mk <<= 1)
#pragma unroll
            for (int r = 0; r < 4; ++r)
                tsum[r] += __shfl_xor(tsum[r], mk, 64);
#pragma unroll
        for (int r = 0; r < 4; ++r) l_r[r] = l_r[r] * alpha[r] + tsum[r];
#pragma unroll
        for (int df = 0; df < 4; ++df)
#pragma unroll
            for (int r = 0; r < 4; ++r) oacc[df][r] *= alpha[r];

        // --- O += P V ---
        bf16x8 pf0 = *(const bf16x8*)((char*)p_lds + wq * 2048 + c15 * 128 +
                                      ((g * 16) ^ ((c15 & 7) << 4)));
        bf16x8 pf1 = *(const bf16x8*)((char*)p_lds + wq * 2048 + c15 * 128 +
                                      ((64 + g * 16) ^ ((c15 & 7) << 4)));
#pragma unroll
        for (int df = 0; df < 4; ++df) {
            const int d = df * 16 + c15;
            bf16x8 vf0 = *(const bf16x8*)((char*)v_lds + d * 128 + ((g * 16) ^ ((d & 7) << 4)));
            bf16x8 vf1 = *(const bf16x8*)((char*)v_lds + d * 128 + ((64 + g * 16) ^ ((d & 7) << 4)));
            oacc[df] = __builtin_amdgcn_mfma_f32_16x16x32_bf16(pf0, vf0, oacc[df], 0, 0, 0);
            oacc[df] = __builtin_amdgcn_mfma_f32_16x16x32_bf16(pf1, vf1, oacc[df], 0, 0, 0);
        }
    }

    // --- epilogue: O / l ---
    float inv[4];
#pragma unroll
    for (int r = 0; r < 4; ++r) inv[r] = 1.0f / l_r[r];
    float* outp = out + (size_t)b * S_ * DOUT;
#pragma unroll
    for (int df = 0; df < 4; ++df)
#pragma unroll
        for (int r = 0; r < 4; ++r)
            outp[(size_t)(q0 + wq * 16 + g * 4 + r) * DOUT + df * 16 + c15] = oacc[df][r] * inv[r];
}

// ---------------------------------------------------------------------------
extern "C" void kernel_launch(void* const* d_in, const int* in_sizes, int n_in,
                              void* d_out, int out_size, void* d_ws, size_t ws_size,
                              hipStream_t stream) {
    const float* x  = (const float*)d_in[0];
    const float* WQ = (const float*)d_in[1];
    const float* WK = (const float*)d_in[2];
    const float* WV = (const float*)d_in[3];

    unsigned short* Wt  = (unsigned short*)d_ws;                 // 192*512*2 = 192 KB
    unsigned short* QKV = Wt + 192 * 512;                        // 3*32768*64*2 = 12 MB

    wt_convert<<<96, 256, 0, stream>>>(WQ, WK, WV, Wt);
    qkv_proj<<<512, 256, 0, stream>>>(x, Wt, QKV);
    attn_fwd<<<512, 256, 0, stream>>>(QKV, (float*)d_out);
}

// Round 3
// 157.263 us; speedup vs baseline: 1.3681x; 1.3681x over previous
//
#include <hip/hip_runtime.h>
#include <hip/hip_bf16.h>

#define B_    8
#define S_    4096
#define DIN   512
#define DOUT  64
#define NROWS (B_ * S_)   // 32768

typedef __attribute__((ext_vector_type(8))) short bf16x8;
typedef __attribute__((ext_vector_type(4))) float f32x4;
typedef __attribute__((ext_vector_type(2))) unsigned int u32x2;

typedef const __attribute__((address_space(1))) unsigned int GUI;
typedef __attribute__((address_space(3))) unsigned int LUI;

__device__ __forceinline__ unsigned short f32_to_bf16(float f) {
    union { float f; unsigned int u; } c; c.f = f;
    unsigned int r = (c.u + 0x7FFFu + ((c.u >> 16) & 1u)) >> 16;
    return (unsigned short)r;
}

// ---------------------------------------------------------------------------
// Kernel 1: transpose W_Q|W_K|W_V (each [512][64] f32) -> Wt bf16 [192][512]
// ---------------------------------------------------------------------------
__global__ void wt_convert(const float* __restrict__ WQ,
                           const float* __restrict__ WK,
                           const float* __restrict__ WV,
                           unsigned short* __restrict__ Wt) {
    int idx = blockIdx.x * 256 + threadIdx.x;
    if (idx >= 3 * 512 * 16) return;
    int p   = idx / 8192;
    int rem = idx - p * 8192;
    int k   = rem >> 4;
    int n0  = (rem & 15) * 4;
    const float* W = (p == 0) ? WQ : ((p == 1) ? WK : WV);
    float4 v = *(const float4*)(W + k * 64 + n0);
    Wt[(size_t)(p * 64 + n0 + 0) * 512 + k] = f32_to_bf16(v.x);
    Wt[(size_t)(p * 64 + n0 + 1) * 512 + k] = f32_to_bf16(v.y);
    Wt[(size_t)(p * 64 + n0 + 2) * 512 + k] = f32_to_bf16(v.z);
    Wt[(size_t)(p * 64 + n0 + 3) * 512 + k] = f32_to_bf16(v.w);
}

// ---------------------------------------------------------------------------
// Kernel 2: fused QKV projection. Q,K stored [b][s][d] (Q pre-scaled 1/8);
// V stored TRANSPOSED [b][d][s] so attention can stage V^T tiles with
// contiguous 16B global_load_lds (no on-the-fly transpose needed).
// ---------------------------------------------------------------------------
__global__ __launch_bounds__(256) void qkv_proj(const float* __restrict__ x,
                                                const unsigned short* __restrict__ Wt,
                                                unsigned short* __restrict__ QKV) {
    const int tid  = threadIdx.x;
    const int lane = tid & 63;
    const int wq   = tid >> 6;
    const int c15  = lane & 15;
    const int g    = lane >> 4;
    const int arow = blockIdx.x * 64 + wq * 16 + c15;
    const float* xrow = x + (size_t)arow * DIN;

    f32x4 acc[12] = {};

    for (int ks = 0; ks < 16; ++ks) {
        const float4* ap = (const float4*)(xrow + ks * 32 + g * 8);
        float4 a0 = ap[0], a1 = ap[1];
        bf16x8 af;
        af[0] = (short)f32_to_bf16(a0.x); af[1] = (short)f32_to_bf16(a0.y);
        af[2] = (short)f32_to_bf16(a0.z); af[3] = (short)f32_to_bf16(a0.w);
        af[4] = (short)f32_to_bf16(a1.x); af[5] = (short)f32_to_bf16(a1.y);
        af[6] = (short)f32_to_bf16(a1.z); af[7] = (short)f32_to_bf16(a1.w);
#pragma unroll
        for (int nf = 0; nf < 12; ++nf) {
            bf16x8 bf = *(const bf16x8*)(Wt + (size_t)(nf * 16 + c15) * 512 + ks * 32 + g * 8);
            acc[nf] = __builtin_amdgcn_mfma_f32_16x16x32_bf16(af, bf, acc[nf], 0, 0, 0);
        }
    }

    const int orow0 = blockIdx.x * 64 + wq * 16 + g * 4;   // rows orow0..orow0+3
#pragma unroll
    for (int nf = 0; nf < 12; ++nf) {
        const int p    = nf >> 2;
        const int ncol = (nf & 3) * 16 + c15;
        if (p < 2) {
            unsigned short* outp = QKV + (size_t)p * NROWS * DOUT;
            const float sc = (p == 0) ? 0.125f : 1.0f;   // fold 1/sqrt(64) into Q
#pragma unroll
            for (int r = 0; r < 4; ++r)
                outp[(size_t)(orow0 + r) * DOUT + ncol] = f32_to_bf16(acc[nf][r] * sc);
        } else {
            // V^T[b][ncol][srow..srow+3], 4 bf16 packed into one 8B store
            const int bb   = orow0 >> 12;
            const int srow = orow0 & 4095;
            union { unsigned short s[4]; u32x2 d; } pk;
#pragma unroll
            for (int r = 0; r < 4; ++r) pk.s[r] = f32_to_bf16(acc[nf][r]);
            *(u32x2*)(QKV + (size_t)2 * NROWS * DOUT +
                      ((size_t)bb * DOUT + ncol) * S_ + srow) = pk.d;
        }
    }
}

// ---------------------------------------------------------------------------
// Kernel 3: causal flash attention, S^T/O^T formulation.
// Grid 512 (8 batches x 64 q-tiles, heavy-first), 256 thr = 4 waves x 16 q.
// S^T = mfma(K, Q): lane c15 = q -> softmax fully lane-local.
// O^T = mfma(V^T, P^T); V^T tile staged row-major like K (from [b][d][s]).
// 3-buffer global_load_lds pipeline: one raw s_barrier + vmcnt(4) per iter.
// ---------------------------------------------------------------------------
__global__ __launch_bounds__(256) void attn_fwd(const unsigned short* __restrict__ QKV,
                                                float* __restrict__ out) {
    __shared__ alignas(16) unsigned short k_lds[3][4096]; // K[kv][8 slots], slot^=(kv&7)
    __shared__ alignas(16) unsigned short v_lds[3][4096]; // V^T[d][8 slots], slot^=(d&7)
    __shared__ alignas(16) unsigned short p_lds[4][1024]; // per-wave P[q][kv], swizzled

    const int bid  = blockIdx.x;
    const int b    = bid & 7;             // batch == bid%8 -> per-XCD L2 affinity
    const int t    = 63 - (bid >> 3);     // heavy q-tiles first
    const int q0   = t * 64;
    const int tid  = threadIdx.x;
    const int lane = tid & 63;
    const int wq   = tid >> 6;
    const int c15  = lane & 15;
    const int g    = lane >> 4;

    const unsigned short* Qg  = QKV + (size_t)b * S_ * DOUT;
    const unsigned short* Kg  = QKV + (size_t)NROWS * DOUT + (size_t)b * S_ * DOUT;
    const unsigned short* VTg = QKV + (size_t)2 * NROWS * DOUT + (size_t)b * DOUT * S_;

    // Q as B-operand: lane gives Q[q = q0+wq*16+c15][d = 32*kk + 8*g + j]
    const size_t qoff = (size_t)(q0 + wq * 16 + c15) * DOUT;
    bf16x8 qf0 = *(const bf16x8*)(Qg + qoff + g * 8);
    bf16x8 qf1 = *(const bf16x8*)(Qg + qoff + 32 + g * 8);
    asm volatile("s_waitcnt vmcnt(0)" ::: "memory");  // exact vmcnt bookkeeping

    const int nt = t + 1;

    // staging geometry: chunk i -> (row = i>>3, dest slot = i&7, src slot ^ row&7)
    const int i0 = wq * 128 + lane;
    const int i1 = i0 + 64;
    const int r0 = i0 >> 3, s0 = (i0 & 7) ^ (r0 & 7);
    const int r1 = i1 >> 3, s1 = (i1 & 7) ^ (r1 & 7);

    auto stage = [&](int slot, int tt) {
        const unsigned short* Kt = Kg + (size_t)tt * 64 * DOUT;
        const unsigned short* Vt = VTg + tt * 64;            // column offset in [d][s]
        char* kbase = (char*)&k_lds[slot][0] + wq * 2048;
        char* vbase = (char*)&v_lds[slot][0] + wq * 2048;
        __builtin_amdgcn_global_load_lds((GUI*)(Kt + r0 * DOUT + s0 * 8), (LUI*)kbase, 16, 0, 0);
        __builtin_amdgcn_global_load_lds((GUI*)(Kt + r1 * DOUT + s1 * 8), (LUI*)(kbase + 1024), 16, 0, 0);
        __builtin_amdgcn_global_load_lds((GUI*)(Vt + (size_t)r0 * S_ + s0 * 8), (LUI*)vbase, 16, 0, 0);
        __builtin_amdgcn_global_load_lds((GUI*)(Vt + (size_t)r1 * S_ + s1 * 8), (LUI*)(vbase + 1024), 16, 0, 0);
    };

    stage(0, 0);
    stage(1, nt > 1 ? 1 : 0);

    f32x4 oacc[4] = {};
    float m_r = -3.0e38f, l_r = 0.f;

    int cur = 0;
    for (int it = 0; it < nt; ++it) {
        // own-wave oldest 4 (buf cur) drained; barrier makes it true block-wide.
        asm volatile("s_waitcnt vmcnt(4)" ::: "memory");
        asm volatile("s_barrier" ::: "memory");

        {   // prefetch tile it+2 (clamped so vmcnt arithmetic stays uniform)
            int tn = it + 2; if (tn >= nt) tn = nt - 1;
            int slot = cur + 2; if (slot >= 3) slot -= 3;
            stage(slot, tn);
        }

        const char* kb = (const char*)&k_lds[cur][0];
        const char* vb = (const char*)&v_lds[cur][0];

        // --- S^T = mfma(K, Q): lane holds S^T[kv = 16nf+4g+r][q = c15] ---
        f32x4 s[4];
#pragma unroll
        for (int nf = 0; nf < 4; ++nf) {
            const char* krow = kb + (nf * 16 + c15) * 128;
            bf16x8 kf0 = *(const bf16x8*)(krow + ((g ^ (c15 & 7)) << 4));
            bf16x8 kf1 = *(const bf16x8*)(krow + (((4 + g) ^ (c15 & 7)) << 4));
            f32x4 z = {};
            z = __builtin_amdgcn_mfma_f32_16x16x32_bf16(kf0, qf0, z, 0, 0, 0);
            z = __builtin_amdgcn_mfma_f32_16x16x32_bf16(kf1, qf1, z, 0, 0, 0);
            s[nf] = z;
        }

        // --- causal mask on diagonal tile (k0 == q0): kv_loc > q_loc ---
        if (it == t) {
            const int ql = wq * 16 + c15;
#pragma unroll
            for (int nf = 0; nf < 4; ++nf)
#pragma unroll
                for (int r = 0; r < 4; ++r)
                    if (16 * nf + 4 * g + r > ql) s[nf][r] = -1.0e30f;
        }

        // --- lane-local online softmax (q = c15; partners at lane^16, ^32) ---
        float mx = s[0][0];
#pragma unroll
        for (int nf = 0; nf < 4; ++nf)
#pragma unroll
            for (int r = 0; r < 4; ++r) mx = fmaxf(mx, s[nf][r]);
        mx = fmaxf(mx, __shfl_xor(mx, 16, 64));
        mx = fmaxf(mx, __shfl_xor(mx, 32, 64));
        const float mnew = fmaxf(m_r, mx);
        const float alpha = __expf(m_r - mnew);
        m_r = mnew;

        float p[4][4];
        float sum = 0.f;
#pragma unroll
        for (int nf = 0; nf < 4; ++nf)
#pragma unroll
            for (int r = 0; r < 4; ++r) {
                p[nf][r] = __expf(s[nf][r] - mnew);
                sum += p[nf][r];
            }
        sum += __shfl_xor(sum, 16, 64);
        sum += __shfl_xor(sum, 32, 64);
        l_r = l_r * alpha + sum;
#pragma unroll
        for (int df = 0; df < 4; ++df)
#pragma unroll
            for (int r = 0; r < 4; ++r) oacc[df][r] *= alpha;

        // --- P^T -> bf16 pairs into per-wave swizzled LDS (w = kv/2) ---
#pragma unroll
        for (int nf = 0; nf < 4; ++nf)
#pragma unroll
            for (int pr = 0; pr < 2; ++pr) {
                unsigned pw;
                asm("v_cvt_pk_bf16_f32 %0, %1, %2"
                    : "=v"(pw) : "v"(p[nf][2 * pr]), "v"(p[nf][2 * pr + 1]));
                const int w = 8 * nf + 2 * g + pr;
                *(unsigned*)((char*)&p_lds[wq][0] + c15 * 128 +
                             (((w >> 2) ^ (c15 & 7)) << 4) + (w & 3) * 4) = pw;
            }

        // --- P^T B-frags: lane gives P[q=c15][kv = 32kk + 8g + j] ---
        bf16x8 pf[2];
#pragma unroll
        for (int kk = 0; kk < 2; ++kk)
            pf[kk] = *(const bf16x8*)((char*)&p_lds[wq][0] + c15 * 128 +
                                      (((4 * kk + g) ^ (c15 & 7)) << 4));

        // --- O^T += mfma(V^T, P^T): lane holds O^T[d = 16df+4g+r][q = c15] ---
#pragma unroll
        for (int df = 0; df < 4; ++df) {
            const char* vrow = vb + (df * 16 + c15) * 128;
            bf16x8 vf0 = *(const bf16x8*)(vrow + ((g ^ (c15 & 7)) << 4));
            bf16x8 vf1 = *(const bf16x8*)(vrow + (((4 + g) ^ (c15 & 7)) << 4));
            oacc[df] = __builtin_amdgcn_mfma_f32_16x16x32_bf16(vf0, pf[0], oacc[df], 0, 0, 0);
            oacc[df] = __builtin_amdgcn_mfma_f32_16x16x32_bf16(vf1, pf[1], oacc[df], 0, 0, 0);
        }

        cur += 1; if (cur >= 3) cur = 0;
    }

    // drain all LDS-DMA before this block's LDS can be reallocated (endpgm hazard)
    asm volatile("s_waitcnt vmcnt(0)" ::: "memory");

    // --- epilogue: out[q][d] = O^T[d][q] / l ---
    const float linv = 1.0f / l_r;
    float* outp = out + (size_t)b * S_ * DOUT + (size_t)(q0 + wq * 16 + c15) * DOUT;
#pragma unroll
    for (int df = 0; df < 4; ++df)
#pragma unroll
        for (int r = 0; r < 4; ++r)
            outp[df * 16 + 4 * g + r] = oacc[df][r] * linv;
}

// ---------------------------------------------------------------------------
extern "C" void kernel_launch(void* const* d_in, const int* in_sizes, int n_in,
                              void* d_out, int out_size, void* d_ws, size_t ws_size,
                              hipStream_t stream) {
    const float* x  = (const float*)d_in[0];
    const float* WQ = (const float*)d_in[1];
    const float* WK = (const float*)d_in[2];
    const float* WV = (const float*)d_in[3];

    unsigned short* Wt  = (unsigned short*)d_ws;   // 192 KB
    unsigned short* QKV = Wt + 192 * 512;          // 12 MB: Q | K | V^T

    wt_convert<<<96, 256, 0, stream>>>(WQ, WK, WV, Wt);
    qkv_proj<<<512, 256, 0, stream>>>(x, Wt, QKV);
    attn_fwd<<<512, 256, 0, stream>>>(QKV, (float*)d_out);
}